// Round 1
// baseline (293.776 us; speedup 1.0000x reference)
//
#include <hip/hip_runtime.h>

using short8 = __attribute__((ext_vector_type(8))) short;
using f32x4  = __attribute__((ext_vector_type(4))) float;

#define SCALE_Q 0.17677669529663687f   // 32^-0.5

__device__ __forceinline__ unsigned short f2bf(float f) {
  unsigned u = __float_as_uint(f);
  return (unsigned short)((u + 0x7FFFu + ((u >> 16) & 1u)) >> 16);  // RNE
}
__device__ __forceinline__ float bf2f(unsigned h) { return __uint_as_float(h << 16); }

__device__ __forceinline__ void bf8_to_f(uint4 r, float* o) {
  o[0] = bf2f(r.x & 0xffffu); o[1] = bf2f(r.x >> 16);
  o[2] = bf2f(r.y & 0xffffu); o[3] = bf2f(r.y >> 16);
  o[4] = bf2f(r.z & 0xffffu); o[5] = bf2f(r.z >> 16);
  o[6] = bf2f(r.w & 0xffffu); o[7] = bf2f(r.w >> 16);
}
__device__ __forceinline__ unsigned pack2(float a, float b) {
  return (unsigned)f2bf(a) | ((unsigned)f2bf(b) << 16);
}

// ---------------- prep: x fp32 -> bf16; transpose-convert weights ----------------
// grid: 16384 blocks for x (4 elem/thread), then 768 for w_qkv^T rows, then 256 for w_out^T rows
__global__ __launch_bounds__(256) void prep_kernel(
    const float* __restrict__ x, const float* __restrict__ wqkv, const float* __restrict__ wout,
    unsigned short* __restrict__ xb, unsigned short* __restrict__ wqkvT,
    unsigned short* __restrict__ woutT) {
  const int blk = blockIdx.x;
  if (blk < 16384) {
    const size_t i = ((size_t)blk * 256 + threadIdx.x) * 4;
    const float4 v = *(const float4*)(x + i);
    *(ushort4*)(xb + i) = make_ushort4(f2bf(v.x), f2bf(v.y), f2bf(v.z), f2bf(v.w));
  } else if (blk < 16384 + 768) {
    const int n = blk - 16384, k = threadIdx.x;            // wqkvT[n][k] = wqkv[k][n]
    wqkvT[n * 256 + k] = f2bf(wqkv[(size_t)k * 768 + n]);
  } else {
    const int c = blk - 16384 - 768, f = threadIdx.x;      // woutT[c][f] = wout[f][c]
    woutT[c * 256 + f] = f2bf(wout[(size_t)f * 256 + c]);
  }
}

// ---------------- GEMM: D[M][N] = A[M][K](bf16) * BT[N][K]^T(bf16) ----------------
// 128x128 tile, BK=32, 4 waves (2x2), each wave 64x64 via 4x4 frags of 16x16x32 MFMA.
template <typename OutT>
__global__ __launch_bounds__(256) void gemm_bt(
    const unsigned short* __restrict__ A, const unsigned short* __restrict__ BT,
    OutT* __restrict__ D, int M, int N, int K) {
  __shared__ unsigned short As[128][40];  // +8 pad: conflict-free b128 frag reads
  __shared__ unsigned short Bs[128][40];
  const int bn = blockIdx.x, bm = blockIdx.y;
  const int tid = threadIdx.x, lane = tid & 63, wid = tid >> 6;
  const int wr = wid >> 1, wc = wid & 1;
  const int fr = lane & 15, fk = (lane >> 4) * 8;
  f32x4 acc[4][4] = {};
  const size_t abase = (size_t)bm * 128 * K;
  const size_t bbase = (size_t)bn * 128 * K;

  for (int kt = 0; kt < K; kt += 32) {
    for (int c = tid; c < 512; c += 256) {          // 512 chunks of 8 bf16
      const int row = c >> 2, kc = (c & 3) * 8;
      *(uint4*)&As[row][kc] = *(const uint4*)(A + abase + (size_t)row * K + kt + kc);
      *(uint4*)&Bs[row][kc] = *(const uint4*)(BT + bbase + (size_t)row * K + kt + kc);
    }
    __syncthreads();
    short8 af[4], bfr[4];
#pragma unroll
    for (int i = 0; i < 4; ++i) {
      af[i]  = *(const short8*)&As[wr * 64 + i * 16 + fr][fk];
      bfr[i] = *(const short8*)&Bs[wc * 64 + i * 16 + fr][fk];
    }
#pragma unroll
    for (int mi = 0; mi < 4; ++mi)
#pragma unroll
      for (int nj = 0; nj < 4; ++nj)
        acc[mi][nj] = __builtin_amdgcn_mfma_f32_16x16x32_bf16(af[mi], bfr[nj], acc[mi][nj], 0, 0, 0);
    __syncthreads();
  }
  // C/D layout (HW-verified): col = lane&15, row = (lane>>4)*4 + reg
  const size_t r0 = (size_t)bm * 128 + wr * 64;
  const int c0 = bn * 128 + wc * 64;
#pragma unroll
  for (int mi = 0; mi < 4; ++mi)
#pragma unroll
    for (int nj = 0; nj < 4; ++nj) {
      const int col = c0 + nj * 16 + fr;
#pragma unroll
      for (int r = 0; r < 4; ++r) {
        const size_t row = r0 + mi * 16 + (lane >> 4) * 4 + r;
        const float v = acc[mi][nj][r];
        if constexpr (sizeof(OutT) == 2) D[row * N + col] = (OutT)f2bf(v);
        else                             D[row * N + col] = v;
      }
    }
}

// ---------------- ctx: per (b,h): k row-softmax over n, context[d][e] -------------
// 128 blocks x 256 threads. thread: d = tid&31, group g = tid>>5 (8 n-strides).
__global__ __launch_bounds__(256) void ctx_kernel(const unsigned short* __restrict__ qkv,
                                                  float* __restrict__ ctx) {
  const int bh = blockIdx.x, b = bh >> 3, h = bh & 7;
  const int tid = threadIdx.x, d = tid & 31, g = tid >> 5;
  const unsigned short* kbase = qkv + (size_t)b * 4096 * 768 + 256 + h * 32;
  const unsigned short* vbase = kbase + 256;

  // phase 1: online max/sumexp over this thread's n-subset (batched loads: 1 wave/SIMD!)
  float m = -3.0e38f, s = 0.0f;
  for (int n = g; n < 4096; n += 64) {
    float vals[8];
#pragma unroll
    for (int j = 0; j < 8; ++j) vals[j] = bf2f(kbase[(size_t)(n + j * 8) * 768 + d]);
#pragma unroll
    for (int j = 0; j < 8; ++j) {
      const float val = vals[j];
      if (val > m) { s = s * __expf(m - val) + 1.0f; m = val; }
      else         { s += __expf(val - m); }
    }
  }
  __shared__ float smx[8][32], sms[8][32];
  __shared__ float kM[32], kSi[32];
  smx[g][d] = m; sms[g][d] = s;
  __syncthreads();
  if (tid < 32) {
    float M = smx[0][tid];
#pragma unroll
    for (int j = 1; j < 8; ++j) M = fmaxf(M, smx[j][tid]);
    float S = 0.0f;
#pragma unroll
    for (int j = 0; j < 8; ++j) S += sms[j][tid] * __expf(smx[j][tid] - M);
    kM[tid] = M; kSi[tid] = 1.0f / S;
  }
  __syncthreads();

  // phase 2: context[d][e] = sum_n exp(k[d,n]-M_d) * v[e,n], chunked + prefetched
  __shared__ float ek[64][36], vv[64][36];
  float a0 = 0.f, a1 = 0.f, a2 = 0.f, a3 = 0.f;
  const int e0 = g * 4;
  const int sn = tid >> 2, sc = (tid & 3) * 8;
  const unsigned short* kp0 = kbase + (size_t)sn * 768 + sc;
  const unsigned short* vp0 = vbase + (size_t)sn * 768 + sc;
  uint4 kr = *(const uint4*)kp0;
  uint4 vr = *(const uint4*)vp0;
  for (int n0 = 0; n0 < 4096; n0 += 64) {
    float kf[8], vf[8];
    bf8_to_f(kr, kf); bf8_to_f(vr, vf);
    uint4 krn = kr, vrn = vr;
    if (n0 + 64 < 4096) {  // prefetch next chunk under this chunk's compute
      krn = *(const uint4*)(kp0 + (size_t)(n0 + 64) * 768);
      vrn = *(const uint4*)(vp0 + (size_t)(n0 + 64) * 768);
    }
#pragma unroll
    for (int j = 0; j < 8; ++j) {
      ek[sn][sc + j] = __expf(kf[j] - kM[sc + j]);
      vv[sn][sc + j] = vf[j];
    }
    __syncthreads();
#pragma unroll 8
    for (int i = 0; i < 64; ++i) {
      const float kd = ek[i][d];
      const float4 v4 = *(const float4*)&vv[i][e0];
      a0 += kd * v4.x; a1 += kd * v4.y; a2 += kd * v4.z; a3 += kd * v4.w;
    }
    __syncthreads();
    kr = krn; vr = vrn;
  }
  const float si = kSi[d];
  float* cp = ctx + (size_t)bh * 1024 + d * 32 + e0;
  cp[0] = a0 * si; cp[1] = a1 * si; cp[2] = a2 * si; cp[3] = a3 * si;
}

// ---------------- attn-out: per n: softmax_d(q)*SCALE, out[e] = ctx[:,e].qs ------
// grid 1024 = 128 bh x 8 n-chunks of 512; 256 threads, 2 n each.
__global__ __launch_bounds__(256) void attn_out_kernel(
    const unsigned short* __restrict__ qkv, const float* __restrict__ ctx,
    unsigned short* __restrict__ attn) {
  const int blk = blockIdx.x, bh = blk >> 3, chunk = blk & 7;
  const int b = bh >> 3, h = bh & 7;
  __shared__ float cs[32][32];
  for (int i = threadIdx.x; i < 1024; i += 256) cs[i >> 5][i & 31] = ctx[(size_t)bh * 1024 + i];
  __syncthreads();
  const unsigned short* qbase = qkv + (size_t)b * 4096 * 768 + h * 32;
  unsigned short* obase = attn + (size_t)b * 4096 * 256 + h * 32;
#pragma unroll
  for (int it = 0; it < 2; ++it) {
    const int n = chunk * 512 + it * 256 + threadIdx.x;
    const unsigned short* qp = qbase + (size_t)n * 768;
    float q[32];
    bf8_to_f(*(const uint4*)(qp + 0),  q + 0);
    bf8_to_f(*(const uint4*)(qp + 8),  q + 8);
    bf8_to_f(*(const uint4*)(qp + 16), q + 16);
    bf8_to_f(*(const uint4*)(qp + 24), q + 24);
    float mx = q[0];
#pragma unroll
    for (int j = 1; j < 32; ++j) mx = fmaxf(mx, q[j]);
    float ssum = 0.f;
#pragma unroll
    for (int j = 0; j < 32; ++j) { q[j] = __expf(q[j] - mx); ssum += q[j]; }
    const float inv = SCALE_Q / ssum;
    float oacc[32] = {};
#pragma unroll
    for (int dd = 0; dd < 32; ++dd) {
      const float qd = q[dd];
#pragma unroll
      for (int eq = 0; eq < 8; ++eq) {
        const float4 c4 = *(const float4*)&cs[dd][eq * 4];  // broadcast read
        oacc[eq * 4 + 0] += qd * c4.x; oacc[eq * 4 + 1] += qd * c4.y;
        oacc[eq * 4 + 2] += qd * c4.z; oacc[eq * 4 + 3] += qd * c4.w;
      }
    }
    uint4* op = (uint4*)(obase + (size_t)n * 256);
    op[0] = make_uint4(pack2(oacc[0]*inv,  oacc[1]*inv),  pack2(oacc[2]*inv,  oacc[3]*inv),
                       pack2(oacc[4]*inv,  oacc[5]*inv),  pack2(oacc[6]*inv,  oacc[7]*inv));
    op[1] = make_uint4(pack2(oacc[8]*inv,  oacc[9]*inv),  pack2(oacc[10]*inv, oacc[11]*inv),
                       pack2(oacc[12]*inv, oacc[13]*inv), pack2(oacc[14]*inv, oacc[15]*inv));
    op[2] = make_uint4(pack2(oacc[16]*inv, oacc[17]*inv), pack2(oacc[18]*inv, oacc[19]*inv),
                       pack2(oacc[20]*inv, oacc[21]*inv), pack2(oacc[22]*inv, oacc[23]*inv));
    op[3] = make_uint4(pack2(oacc[24]*inv, oacc[25]*inv), pack2(oacc[26]*inv, oacc[27]*inv),
                       pack2(oacc[28]*inv, oacc[29]*inv), pack2(oacc[30]*inv, oacc[31]*inv));
  }
}

extern "C" void kernel_launch(void* const* d_in, const int* in_sizes, int n_in,
                              void* d_out, int out_size, void* d_ws, size_t ws_size,
                              hipStream_t stream) {
  const float* x     = (const float*)d_in[0];  // [16,64,64,256]
  const float* wqkv  = (const float*)d_in[1];  // [256,768]
  const float* wout  = (const float*)d_in[2];  // [256,256]
  float* out = (float*)d_out;                  // [65536,256] fp32

  char* ws = (char*)d_ws;
  unsigned short* xb    = (unsigned short*)(ws);                 // 32 MB
  unsigned short* wqkvT = (unsigned short*)(ws + 33554432);      // 384 KB
  unsigned short* woutT = (unsigned short*)(ws + 33947648);      // 128 KB
  unsigned short* qkv   = (unsigned short*)(ws + 34078720);      // 96 MB [65536][768]
  float*          ctx   = (float*)        (ws + 134742016);      // 512 KB [128][32][32]
  unsigned short* attn  = (unsigned short*)(ws + 135266304);     // 32 MB [65536][256]

  prep_kernel<<<16384 + 768 + 256, 256, 0, stream>>>(x, wqkv, wout, xb, wqkvT, woutT);
  gemm_bt<unsigned short><<<dim3(6, 512), 256, 0, stream>>>(xb, wqkvT, qkv, 65536, 768, 256);
  ctx_kernel<<<128, 256, 0, stream>>>(qkv, ctx);
  attn_out_kernel<<<1024, 256, 0, stream>>>(qkv, ctx, attn);
  gemm_bt<float><<<dim3(2, 512), 256, 0, stream>>>(attn, woutT, out, 65536, 256, 256);
}

// Round 2
// 205.085 us; speedup vs baseline: 1.4325x; 1.4325x over previous
//
#include <hip/hip_runtime.h>

using short8 = __attribute__((ext_vector_type(8))) short;
using f32x4  = __attribute__((ext_vector_type(4))) float;

#define SCALE_Q 0.17677669529663687f   // 32^-0.5
#define NCHUNK 16

__device__ __forceinline__ unsigned short f2bf(float f) {
  unsigned u = __float_as_uint(f);
  return (unsigned short)((u + 0x7FFFu + ((u >> 16) & 1u)) >> 16);  // RNE
}
__device__ __forceinline__ float bf2f(unsigned h) { return __uint_as_float(h << 16); }

__device__ __forceinline__ void bf8_to_f(uint4 r, float* o) {
  o[0] = bf2f(r.x & 0xffffu); o[1] = bf2f(r.x >> 16);
  o[2] = bf2f(r.y & 0xffffu); o[3] = bf2f(r.y >> 16);
  o[4] = bf2f(r.z & 0xffffu); o[5] = bf2f(r.z >> 16);
  o[6] = bf2f(r.w & 0xffffu); o[7] = bf2f(r.w >> 16);
}
__device__ __forceinline__ unsigned pack2(float a, float b) {
  return (unsigned)f2bf(a) | ((unsigned)f2bf(b) << 16);
}

// ---------------- prep: x fp32 -> bf16; transpose-convert weights ----------------
__global__ __launch_bounds__(256) void prep_kernel(
    const float* __restrict__ x, const float* __restrict__ wqkv, const float* __restrict__ wout,
    unsigned short* __restrict__ xb, unsigned short* __restrict__ wqkvT,
    unsigned short* __restrict__ woutT) {
  const int blk = blockIdx.x;
  if (blk < 16384) {
    const size_t i = ((size_t)blk * 256 + threadIdx.x) * 4;
    const float4 v = *(const float4*)(x + i);
    *(ushort4*)(xb + i) = make_ushort4(f2bf(v.x), f2bf(v.y), f2bf(v.z), f2bf(v.w));
  } else if (blk < 16384 + 768) {
    const int n = blk - 16384, k = threadIdx.x;            // wqkvT[n][k] = wqkv[k][n]
    wqkvT[n * 256 + k] = f2bf(wqkv[(size_t)k * 768 + n]);
  } else {
    const int c = blk - 16384 - 768, f = threadIdx.x;      // woutT[c][f] = wout[f][c]
    woutT[c * 256 + f] = f2bf(wout[(size_t)f * 256 + c]);
  }
}

// ---------------- GEMM: D[M][N] = A[M][K](bf16) * BT[N][K]^T(bf16) ----------------
// 128x128 tile, BK=32, 4 waves (2x2), each wave 64x64 via 4x4 frags of 16x16x32 MFMA.
template <typename OutT>
__global__ __launch_bounds__(256) void gemm_bt(
    const unsigned short* __restrict__ A, const unsigned short* __restrict__ BT,
    OutT* __restrict__ D, int M, int N, int K) {
  __shared__ unsigned short As[128][40];  // +8 pad: conflict-free b128 frag reads
  __shared__ unsigned short Bs[128][40];
  const int bn = blockIdx.x, bm = blockIdx.y;
  const int tid = threadIdx.x, lane = tid & 63, wid = tid >> 6;
  const int wr = wid >> 1, wc = wid & 1;
  const int fr = lane & 15, fk = (lane >> 4) * 8;
  f32x4 acc[4][4] = {};
  const size_t abase = (size_t)bm * 128 * K;
  const size_t bbase = (size_t)bn * 128 * K;

  for (int kt = 0; kt < K; kt += 32) {
    for (int c = tid; c < 512; c += 256) {          // 512 chunks of 8 bf16
      const int row = c >> 2, kc = (c & 3) * 8;
      *(uint4*)&As[row][kc] = *(const uint4*)(A + abase + (size_t)row * K + kt + kc);
      *(uint4*)&Bs[row][kc] = *(const uint4*)(BT + bbase + (size_t)row * K + kt + kc);
    }
    __syncthreads();
    short8 af[4], bfr[4];
#pragma unroll
    for (int i = 0; i < 4; ++i) {
      af[i]  = *(const short8*)&As[wr * 64 + i * 16 + fr][fk];
      bfr[i] = *(const short8*)&Bs[wc * 64 + i * 16 + fr][fk];
    }
#pragma unroll
    for (int mi = 0; mi < 4; ++mi)
#pragma unroll
      for (int nj = 0; nj < 4; ++nj)
        acc[mi][nj] = __builtin_amdgcn_mfma_f32_16x16x32_bf16(af[mi], bfr[nj], acc[mi][nj], 0, 0, 0);
    __syncthreads();
  }
  // C/D layout (HW-verified): col = lane&15, row = (lane>>4)*4 + reg
  const size_t r0 = (size_t)bm * 128 + wr * 64;
  const int c0 = bn * 128 + wc * 64;
#pragma unroll
  for (int mi = 0; mi < 4; ++mi)
#pragma unroll
    for (int nj = 0; nj < 4; ++nj) {
      const int col = c0 + nj * 16 + fr;
#pragma unroll
      for (int r = 0; r < 4; ++r) {
        const size_t row = r0 + mi * 16 + (lane >> 4) * 4 + r;
        const float v = acc[mi][nj][r];
        if constexpr (sizeof(OutT) == 2) D[row * N + col] = (OutT)f2bf(v);
        else                             D[row * N + col] = v;
      }
    }
}

// ---------------- ctx partials: per (b,h,chunk): sum_n exp(k[d,n])*v[e,n] ---------
// grid 2048 = 128 bh x 16 n-chunks of 256 rows; 256 threads: d = tid&31, g = tid>>5.
// No max-subtraction: k ~ N(0,1) (x~N(0,1), glorot w), exp() is fp32-safe; softmax
// normalization happens in the combine kernel via the summed denominators.
__global__ __launch_bounds__(256) void ctx_part_kernel(const unsigned short* __restrict__ qkv,
                                                       float* __restrict__ part,
                                                       float* __restrict__ spart) {
  const int blk = blockIdx.x;
  const int bh = blk >> 4, chunk = blk & 15;
  const int b = bh >> 3, h = bh & 7;
  const int tid = threadIdx.x, d = tid & 31, g = tid >> 5;
  const unsigned short* kbase =
      qkv + (size_t)b * 4096 * 768 + 256 + h * 32 + (size_t)chunk * 256 * 768;
  const unsigned short* vbase = kbase + 256;

  __shared__ float ek[64][36], vv[64][36];
  float a0 = 0.f, a1 = 0.f, a2 = 0.f, a3 = 0.f, ssum = 0.f;
  const int e0 = g * 4;
  const int sn = tid >> 2, sc = (tid & 3) * 8;
  const unsigned short* kp0 = kbase + (size_t)sn * 768 + sc;
  const unsigned short* vp0 = vbase + (size_t)sn * 768 + sc;
  uint4 kr = *(const uint4*)kp0;
  uint4 vr = *(const uint4*)vp0;
  for (int n0 = 0; n0 < 256; n0 += 64) {
    float kf[8], vf[8];
    bf8_to_f(kr, kf); bf8_to_f(vr, vf);
    uint4 krn = kr, vrn = vr;
    if (n0 + 64 < 256) {  // prefetch next sub-chunk under this one's compute
      krn = *(const uint4*)(kp0 + (size_t)(n0 + 64) * 768);
      vrn = *(const uint4*)(vp0 + (size_t)(n0 + 64) * 768);
    }
#pragma unroll
    for (int j = 0; j < 8; ++j) { ek[sn][sc + j] = __expf(kf[j]); vv[sn][sc + j] = vf[j]; }
    __syncthreads();
#pragma unroll 8
    for (int i = 0; i < 64; ++i) {
      const float kd = ek[i][d];
      const float4 v4 = *(const float4*)&vv[i][e0];
      ssum += kd;
      a0 += kd * v4.x; a1 += kd * v4.y; a2 += kd * v4.z; a3 += kd * v4.w;
    }
    __syncthreads();
    kr = krn; vr = vrn;
  }
  float* pp = part + ((size_t)chunk * 128 + bh) * 1024 + d * 32 + e0;
  pp[0] = a0; pp[1] = a1; pp[2] = a2; pp[3] = a3;
  if (g == 0) spart[((size_t)chunk * 128 + bh) * 32 + d] = ssum;
}

// ---------------- ctx combine: ctx[d][e] = sum_c part / sum_c spart ---------------
__global__ __launch_bounds__(256) void ctx_combine_kernel(const float* __restrict__ part,
                                                          const float* __restrict__ spart,
                                                          float* __restrict__ ctx) {
  const int bh = blockIdx.x, tid = threadIdx.x;
  __shared__ float sinv[32];
  if (tid < 32) {
    float s = 0.f;
#pragma unroll
    for (int c = 0; c < NCHUNK; ++c) s += spart[((size_t)c * 128 + bh) * 32 + tid];
    sinv[tid] = 1.0f / s;
  }
  __syncthreads();
  float4 acc = make_float4(0.f, 0.f, 0.f, 0.f);
#pragma unroll
  for (int c = 0; c < NCHUNK; ++c) {
    const float4 p = *(const float4*)(part + ((size_t)c * 128 + bh) * 1024 + tid * 4);
    acc.x += p.x; acc.y += p.y; acc.z += p.z; acc.w += p.w;
  }
  const float si = sinv[tid >> 3];  // d = (tid*4)>>5
  float4* cp = (float4*)(ctx + (size_t)bh * 1024 + tid * 4);
  *cp = make_float4(acc.x * si, acc.y * si, acc.z * si, acc.w * si);
}

// ---------------- attn-out: per n: softmax_d(q)*SCALE, out[e] = ctx[:,e].qs ------
__global__ __launch_bounds__(256) void attn_out_kernel(
    const unsigned short* __restrict__ qkv, const float* __restrict__ ctx,
    unsigned short* __restrict__ attn) {
  const int blk = blockIdx.x, bh = blk >> 3, chunk = blk & 7;
  const int b = bh >> 3, h = bh & 7;
  __shared__ float cs[32][32];
  for (int i = threadIdx.x; i < 1024; i += 256) cs[i >> 5][i & 31] = ctx[(size_t)bh * 1024 + i];
  __syncthreads();
  const unsigned short* qbase = qkv + (size_t)b * 4096 * 768 + h * 32;
  unsigned short* obase = attn + (size_t)b * 4096 * 256 + h * 32;
#pragma unroll
  for (int it = 0; it < 2; ++it) {
    const int n = chunk * 512 + it * 256 + threadIdx.x;
    const unsigned short* qp = qbase + (size_t)n * 768;
    float q[32];
    bf8_to_f(*(const uint4*)(qp + 0),  q + 0);
    bf8_to_f(*(const uint4*)(qp + 8),  q + 8);
    bf8_to_f(*(const uint4*)(qp + 16), q + 16);
    bf8_to_f(*(const uint4*)(qp + 24), q + 24);
    float mx = q[0];
#pragma unroll
    for (int j = 1; j < 32; ++j) mx = fmaxf(mx, q[j]);
    float ssum = 0.f;
#pragma unroll
    for (int j = 0; j < 32; ++j) { q[j] = __expf(q[j] - mx); ssum += q[j]; }
    const float inv = SCALE_Q / ssum;
    float oacc[32] = {};
#pragma unroll
    for (int dd = 0; dd < 32; ++dd) {
      const float qd = q[dd];
#pragma unroll
      for (int eq = 0; eq < 8; ++eq) {
        const float4 c4 = *(const float4*)&cs[dd][eq * 4];  // broadcast read
        oacc[eq * 4 + 0] += qd * c4.x; oacc[eq * 4 + 1] += qd * c4.y;
        oacc[eq * 4 + 2] += qd * c4.z; oacc[eq * 4 + 3] += qd * c4.w;
      }
    }
    uint4* op = (uint4*)(obase + (size_t)n * 256);
    op[0] = make_uint4(pack2(oacc[0]*inv,  oacc[1]*inv),  pack2(oacc[2]*inv,  oacc[3]*inv),
                       pack2(oacc[4]*inv,  oacc[5]*inv),  pack2(oacc[6]*inv,  oacc[7]*inv));
    op[1] = make_uint4(pack2(oacc[8]*inv,  oacc[9]*inv),  pack2(oacc[10]*inv, oacc[11]*inv),
                       pack2(oacc[12]*inv, oacc[13]*inv), pack2(oacc[14]*inv, oacc[15]*inv));
    op[2] = make_uint4(pack2(oacc[16]*inv, oacc[17]*inv), pack2(oacc[18]*inv, oacc[19]*inv),
                       pack2(oacc[20]*inv, oacc[21]*inv), pack2(oacc[22]*inv, oacc[23]*inv));
    op[3] = make_uint4(pack2(oacc[24]*inv, oacc[25]*inv), pack2(oacc[26]*inv, oacc[27]*inv),
                       pack2(oacc[28]*inv, oacc[29]*inv), pack2(oacc[30]*inv, oacc[31]*inv));
  }
}

extern "C" void kernel_launch(void* const* d_in, const int* in_sizes, int n_in,
                              void* d_out, int out_size, void* d_ws, size_t ws_size,
                              hipStream_t stream) {
  const float* x     = (const float*)d_in[0];  // [16,64,64,256]
  const float* wqkv  = (const float*)d_in[1];  // [256,768]
  const float* wout  = (const float*)d_in[2];  // [256,256]
  float* out = (float*)d_out;                  // [65536,256] fp32

  char* ws = (char*)d_ws;
  unsigned short* xb    = (unsigned short*)(ws);                 // 32 MB (dead after gemm1)
  unsigned short* wqkvT = (unsigned short*)(ws + 33554432);      // 384 KB
  unsigned short* woutT = (unsigned short*)(ws + 33947648);      // 128 KB
  unsigned short* qkv   = (unsigned short*)(ws + 34078720);      // 96 MB [65536][768]
  float*          ctx   = (float*)        (ws + 134742016);      // 512 KB [128][32][32]
  unsigned short* attn  = (unsigned short*)(ws + 135266304);     // 32 MB [65536][256]
  // ctx partials reuse the xb region (xb is dead once gemm1 completes, same stream):
  float* part  = (float*)(ws);                                   // 8 MB [16][128][1024]
  float* spart = (float*)(ws + 8388608);                         // 256 KB [16][128][32]

  prep_kernel<<<16384 + 768 + 256, 256, 0, stream>>>(x, wqkv, wout, xb, wqkvT, woutT);
  gemm_bt<unsigned short><<<dim3(6, 512), 256, 0, stream>>>(xb, wqkvT, qkv, 65536, 768, 256);
  ctx_part_kernel<<<2048, 256, 0, stream>>>(qkv, part, spart);
  ctx_combine_kernel<<<128, 256, 0, stream>>>(part, spart, ctx);
  attn_out_kernel<<<1024, 256, 0, stream>>>(qkv, ctx, attn);
  gemm_bt<float><<<dim3(2, 512), 256, 0, stream>>>(attn, woutT, out, 65536, 256, 256);
}

// Round 3
// 184.942 us; speedup vs baseline: 1.5885x; 1.1089x over previous
//
#include <hip/hip_runtime.h>

using short8 = __attribute__((ext_vector_type(8))) short;
using f32x4  = __attribute__((ext_vector_type(4))) float;

#define SCALE_Q 0.17677669529663687f   // 32^-0.5
#define NCHUNK 16

__device__ __forceinline__ unsigned short f2bf(float f) {
  unsigned u = __float_as_uint(f);
  return (unsigned short)((u + 0x7FFFu + ((u >> 16) & 1u)) >> 16);  // RNE
}
__device__ __forceinline__ float bf2f(unsigned h) { return __uint_as_float(h << 16); }

__device__ __forceinline__ void bf8_to_f(uint4 r, float* o) {
  o[0] = bf2f(r.x & 0xffffu); o[1] = bf2f(r.x >> 16);
  o[2] = bf2f(r.y & 0xffffu); o[3] = bf2f(r.y >> 16);
  o[4] = bf2f(r.z & 0xffffu); o[5] = bf2f(r.z >> 16);
  o[6] = bf2f(r.w & 0xffffu); o[7] = bf2f(r.w >> 16);
}
__device__ __forceinline__ unsigned pack2(float a, float b) {
  return (unsigned)f2bf(a) | ((unsigned)f2bf(b) << 16);
}

// ---------------- prep: x fp32 -> bf16; transpose-convert weights ----------------
__global__ __launch_bounds__(256) void prep_kernel(
    const float* __restrict__ x, const float* __restrict__ wqkv, const float* __restrict__ wout,
    unsigned short* __restrict__ xb, unsigned short* __restrict__ wqkvT,
    unsigned short* __restrict__ woutT) {
  const int blk = blockIdx.x;
  if (blk < 16384) {
    const size_t i = ((size_t)blk * 256 + threadIdx.x) * 4;
    const float4 v = *(const float4*)(x + i);
    *(ushort4*)(xb + i) = make_ushort4(f2bf(v.x), f2bf(v.y), f2bf(v.z), f2bf(v.w));
  } else if (blk < 16384 + 768) {
    const int n = blk - 16384, k = threadIdx.x;            // wqkvT[n][k] = wqkv[k][n]
    wqkvT[n * 256 + k] = f2bf(wqkv[(size_t)k * 768 + n]);
  } else {
    const int c = blk - 16384 - 768, f = threadIdx.x;      // woutT[c][f] = wout[f][c]
    woutT[c * 256 + f] = f2bf(wout[(size_t)f * 256 + c]);
  }
}

// ---------------- GEMM: D[M][N] = A[M][K](bf16) * BT[N][K]^T(bf16), batched -------
// 128x128 tile, BK=32, 4 waves (2x2), each wave 64x64 via 4x4 frags of 16x16x32 MFMA.
template <typename OutT>
__global__ __launch_bounds__(256) void gemm_bt(
    const unsigned short* __restrict__ A, const unsigned short* __restrict__ BT,
    OutT* __restrict__ D, int M, int N, int K,
    size_t strideA, size_t strideB, size_t strideD) {
  __shared__ unsigned short As[128][40];  // +8 pad: conflict-free b128 frag reads
  __shared__ unsigned short Bs[128][40];
  const int bn = blockIdx.x, bm = blockIdx.y, bz = blockIdx.z;
  const int tid = threadIdx.x, lane = tid & 63, wid = tid >> 6;
  const int wr = wid >> 1, wc = wid & 1;
  const int fr = lane & 15, fk = (lane >> 4) * 8;
  f32x4 acc[4][4] = {};
  const size_t abase = (size_t)bz * strideA + (size_t)bm * 128 * K;
  const size_t bbase = (size_t)bz * strideB + (size_t)bn * 128 * K;

  for (int kt = 0; kt < K; kt += 32) {
    for (int c = tid; c < 512; c += 256) {          // 512 chunks of 8 bf16
      const int row = c >> 2, kc = (c & 3) * 8;
      *(uint4*)&As[row][kc] = *(const uint4*)(A + abase + (size_t)row * K + kt + kc);
      *(uint4*)&Bs[row][kc] = *(const uint4*)(BT + bbase + (size_t)row * K + kt + kc);
    }
    __syncthreads();
    short8 af[4], bfr[4];
#pragma unroll
    for (int i = 0; i < 4; ++i) {
      af[i]  = *(const short8*)&As[wr * 64 + i * 16 + fr][fk];
      bfr[i] = *(const short8*)&Bs[wc * 64 + i * 16 + fr][fk];
    }
#pragma unroll
    for (int mi = 0; mi < 4; ++mi)
#pragma unroll
      for (int nj = 0; nj < 4; ++nj)
        acc[mi][nj] = __builtin_amdgcn_mfma_f32_16x16x32_bf16(af[mi], bfr[nj], acc[mi][nj], 0, 0, 0);
    __syncthreads();
  }
  // C/D layout (HW-verified): col = lane&15, row = (lane>>4)*4 + reg
  const size_t r0 = (size_t)bm * 128 + wr * 64;
  const int c0 = bn * 128 + wc * 64;
  OutT* Dz = D + (size_t)bz * strideD;
#pragma unroll
  for (int mi = 0; mi < 4; ++mi)
#pragma unroll
    for (int nj = 0; nj < 4; ++nj) {
      const int col = c0 + nj * 16 + fr;
#pragma unroll
      for (int r = 0; r < 4; ++r) {
        const size_t row = r0 + mi * 16 + (lane >> 4) * 4 + r;
        const float v = acc[mi][nj][r];
        if constexpr (sizeof(OutT) == 2) Dz[row * N + col] = (OutT)f2bf(v);
        else                             Dz[row * N + col] = v;
      }
    }
}

// ---------------- ctx partials: per (b,h,chunk): sum_n exp(k[d,n])*v[e,n] ---------
// grid 2048 = 128 bh x 16 n-chunks of 256 rows; 256 threads: d = tid&31, g = tid>>5.
// No max-subtraction: k ~ N(0,1), exp() fp32-safe; normalization in combine kernel.
__global__ __launch_bounds__(256) void ctx_part_kernel(const unsigned short* __restrict__ qkv,
                                                       float* __restrict__ part,
                                                       float* __restrict__ spart) {
  const int blk = blockIdx.x;
  const int bh = blk >> 4, chunk = blk & 15;
  const int b = bh >> 3, h = bh & 7;
  const int tid = threadIdx.x, d = tid & 31, g = tid >> 5;
  const unsigned short* kbase =
      qkv + (size_t)b * 4096 * 768 + 256 + h * 32 + (size_t)chunk * 256 * 768;
  const unsigned short* vbase = kbase + 256;

  __shared__ float ek[64][36], vv[64][36];
  float a0 = 0.f, a1 = 0.f, a2 = 0.f, a3 = 0.f, ssum = 0.f;
  const int e0 = g * 4;
  const int sn = tid >> 2, sc = (tid & 3) * 8;
  const unsigned short* kp0 = kbase + (size_t)sn * 768 + sc;
  const unsigned short* vp0 = vbase + (size_t)sn * 768 + sc;
  uint4 kr = *(const uint4*)kp0;
  uint4 vr = *(const uint4*)vp0;
  for (int n0 = 0; n0 < 256; n0 += 64) {
    float kf[8], vf[8];
    bf8_to_f(kr, kf); bf8_to_f(vr, vf);
    uint4 krn = kr, vrn = vr;
    if (n0 + 64 < 256) {  // prefetch next sub-chunk under this one's compute
      krn = *(const uint4*)(kp0 + (size_t)(n0 + 64) * 768);
      vrn = *(const uint4*)(vp0 + (size_t)(n0 + 64) * 768);
    }
#pragma unroll
    for (int j = 0; j < 8; ++j) { ek[sn][sc + j] = __expf(kf[j]); vv[sn][sc + j] = vf[j]; }
    __syncthreads();
#pragma unroll 8
    for (int i = 0; i < 64; ++i) {
      const float kd = ek[i][d];
      const float4 v4 = *(const float4*)&vv[i][e0];
      ssum += kd;
      a0 += kd * v4.x; a1 += kd * v4.y; a2 += kd * v4.z; a3 += kd * v4.w;
    }
    __syncthreads();
    kr = krn; vr = vrn;
  }
  float* pp = part + ((size_t)chunk * 128 + bh) * 1024 + d * 32 + e0;
  pp[0] = a0; pp[1] = a1; pp[2] = a2; pp[3] = a3;
  if (g == 0) spart[((size_t)chunk * 128 + bh) * 32 + d] = ssum;
}

// ---------------- ctx combine: ctx[d][e] = sum_c part / sum_c spart ---------------
__global__ __launch_bounds__(256) void ctx_combine_kernel(const float* __restrict__ part,
                                                          const float* __restrict__ spart,
                                                          float* __restrict__ ctx) {
  const int bh = blockIdx.x, tid = threadIdx.x;
  __shared__ float sinv[32];
  if (tid < 32) {
    float s = 0.f;
#pragma unroll
    for (int c = 0; c < NCHUNK; ++c) s += spart[((size_t)c * 128 + bh) * 32 + tid];
    sinv[tid] = 1.0f / s;
  }
  __syncthreads();
  float4 acc = make_float4(0.f, 0.f, 0.f, 0.f);
#pragma unroll
  for (int c = 0; c < NCHUNK; ++c) {
    const float4 p = *(const float4*)(part + ((size_t)c * 128 + bh) * 1024 + tid * 4);
    acc.x += p.x; acc.y += p.y; acc.z += p.z; acc.w += p.w;
  }
  const float si = sinv[tid >> 3];  // d = (tid*4)>>5
  float4* cp = (float4*)(ctx + (size_t)bh * 1024 + tid * 4);
  *cp = make_float4(acc.x * si, acc.y * si, acc.z * si, acc.w * si);
}

// ---------------- qsoftmax: q_hat[n][(h,d)] = softmax_d(q[n,h,:]) * SCALE_Q -------
// 2048 blocks x 256 threads; thread t -> n = t>>3, h = t&7. All in registers.
__global__ __launch_bounds__(256) void qsoftmax_kernel(const unsigned short* __restrict__ qkv,
                                                       unsigned short* __restrict__ qs) {
  const size_t t = (size_t)blockIdx.x * 256 + threadIdx.x;
  const size_t n = t >> 3; const int h = (int)(t & 7);
  const unsigned short* qp = qkv + n * 768 + h * 32;
  float q[32];
  bf8_to_f(*(const uint4*)(qp + 0),  q + 0);
  bf8_to_f(*(const uint4*)(qp + 8),  q + 8);
  bf8_to_f(*(const uint4*)(qp + 16), q + 16);
  bf8_to_f(*(const uint4*)(qp + 24), q + 24);
  float mx = q[0];
#pragma unroll
  for (int j = 1; j < 32; ++j) mx = fmaxf(mx, q[j]);
  float ssum = 0.f;
#pragma unroll
  for (int j = 0; j < 32; ++j) { q[j] = __expf(q[j] - mx); ssum += q[j]; }
  const float inv = SCALE_Q / ssum;
  uint4* op = (uint4*)(qs + n * 256 + h * 32);
  op[0] = make_uint4(pack2(q[0]*inv,  q[1]*inv),  pack2(q[2]*inv,  q[3]*inv),
                     pack2(q[4]*inv,  q[5]*inv),  pack2(q[6]*inv,  q[7]*inv));
  op[1] = make_uint4(pack2(q[8]*inv,  q[9]*inv),  pack2(q[10]*inv, q[11]*inv),
                     pack2(q[12]*inv, q[13]*inv), pack2(q[14]*inv, q[15]*inv));
  op[2] = make_uint4(pack2(q[16]*inv, q[17]*inv), pack2(q[18]*inv, q[19]*inv),
                     pack2(q[20]*inv, q[21]*inv), pack2(q[22]*inv, q[23]*inv));
  op[3] = make_uint4(pack2(q[24]*inv, q[25]*inv), pack2(q[26]*inv, q[27]*inv),
                     pack2(q[28]*inv, q[29]*inv), pack2(q[30]*inv, q[31]*inv));
}

// ---------------- w2: W2T[b][c][(h,d)] = sum_e ctx[b,h,d,e] * woutT[c][(h,e)] -----
// grid 256 = b(16) x cgroup(16); 256 threads: c = cg*16 + (tid>>4), chunk = tid&15
// chunk -> h = chunk>>1, d0 = (chunk&1)*16 (16 d-values per thread).
__global__ __launch_bounds__(256) void w2_kernel(const float* __restrict__ ctx,
                                                 const unsigned short* __restrict__ woutT,
                                                 unsigned short* __restrict__ W2T) {
  const int b = blockIdx.x >> 4, cg = blockIdx.x & 15;
  const int tid = threadIdx.x;
  __shared__ float cs[8 * 32 * 32];  // ctx[b]: 8 heads x 32d x 32e = 32 KB
  {
    const float4* src = (const float4*)(ctx + (size_t)b * 8192);
    float4* dst = (float4*)cs;
#pragma unroll
    for (int i = 0; i < 8; ++i) dst[tid + i * 256] = src[tid + i * 256];
  }
  __syncthreads();
  const int c = cg * 16 + (tid >> 4), chunk = tid & 15;
  const int h = chunk >> 1, d0 = (chunk & 1) * 16;
  float wf[32];
  {
    const uint4* wp = (const uint4*)(woutT + (size_t)c * 256 + h * 32);
    bf8_to_f(wp[0], wf + 0); bf8_to_f(wp[1], wf + 8);
    bf8_to_f(wp[2], wf + 16); bf8_to_f(wp[3], wf + 24);
  }
  unsigned short o[16];
#pragma unroll
  for (int dd = 0; dd < 16; ++dd) {
    const float* cp = cs + h * 1024 + (d0 + dd) * 32;
    float acc = 0.f;
#pragma unroll
    for (int e = 0; e < 32; ++e) acc += cp[e] * wf[e];
    o[dd] = f2bf(acc);
  }
  uint4* op = (uint4*)(W2T + ((size_t)b * 256 + c) * 256 + chunk * 16);
  op[0] = make_uint4((unsigned)o[0] | ((unsigned)o[1] << 16), (unsigned)o[2] | ((unsigned)o[3] << 16),
                     (unsigned)o[4] | ((unsigned)o[5] << 16), (unsigned)o[6] | ((unsigned)o[7] << 16));
  op[1] = make_uint4((unsigned)o[8] | ((unsigned)o[9] << 16), (unsigned)o[10] | ((unsigned)o[11] << 16),
                     (unsigned)o[12] | ((unsigned)o[13] << 16), (unsigned)o[14] | ((unsigned)o[15] << 16));
}

extern "C" void kernel_launch(void* const* d_in, const int* in_sizes, int n_in,
                              void* d_out, int out_size, void* d_ws, size_t ws_size,
                              hipStream_t stream) {
  const float* x     = (const float*)d_in[0];  // [16,64,64,256]
  const float* wqkv  = (const float*)d_in[1];  // [256,768]
  const float* wout  = (const float*)d_in[2];  // [256,256]
  float* out = (float*)d_out;                  // [65536,256] fp32

  char* ws = (char*)d_ws;
  unsigned short* xb    = (unsigned short*)(ws);                 // 32 MB (dead after gemm1)
  unsigned short* wqkvT = (unsigned short*)(ws + 33554432);      // 384 KB
  unsigned short* woutT = (unsigned short*)(ws + 33947648);      // 128 KB
  unsigned short* qkv   = (unsigned short*)(ws + 34078720);      // 96 MB [65536][768]
  float*          ctx   = (float*)        (ws + 134742016);      // 512 KB [128][32][32]
  unsigned short* qs    = (unsigned short*)(ws + 135266304);     // 32 MB [65536][256]
  // reuse xb region (dead after gemm1):
  float*          part  = (float*)(ws);                          // 8 MB [16][128][1024]
  float*          spart = (float*)(ws + 8388608);                // 256 KB [16][128][32]
  unsigned short* W2T   = (unsigned short*)(ws + 12582912);      // 2 MB [16][256][256]

  prep_kernel<<<16384 + 768 + 256, 256, 0, stream>>>(x, wqkv, wout, xb, wqkvT, woutT);
  gemm_bt<unsigned short><<<dim3(6, 512, 1), 256, 0, stream>>>(
      xb, wqkvT, qkv, 65536, 768, 256, 0, 0, 0);
  ctx_part_kernel<<<2048, 256, 0, stream>>>(qkv, part, spart);
  ctx_combine_kernel<<<128, 256, 0, stream>>>(part, spart, ctx);
  qsoftmax_kernel<<<2048, 256, 0, stream>>>(qkv, qs);
  w2_kernel<<<256, 256, 0, stream>>>(ctx, woutT, W2T);
  gemm_bt<float><<<dim3(2, 32, 16), 256, 0, stream>>>(
      qs, W2T, out, 4096, 256, 256, 4096 * 256, 256 * 256, 4096 * 256);
}

// Round 4
// 175.034 us; speedup vs baseline: 1.6784x; 1.0566x over previous
//
#include <hip/hip_runtime.h>

using short8 = __attribute__((ext_vector_type(8))) short;
using f32x4  = __attribute__((ext_vector_type(4))) float;

#define SCALE_Q 0.17677669529663687f   // 32^-0.5
#define NCHUNK 16

__device__ __forceinline__ unsigned short f2bf(float f) {
  unsigned u = __float_as_uint(f);
  return (unsigned short)((u + 0x7FFFu + ((u >> 16) & 1u)) >> 16);  // RNE
}
__device__ __forceinline__ float bf2f(unsigned h) { return __uint_as_float(h << 16); }

__device__ __forceinline__ void bf8_to_f(uint4 r, float* o) {
  o[0] = bf2f(r.x & 0xffffu); o[1] = bf2f(r.x >> 16);
  o[2] = bf2f(r.y & 0xffffu); o[3] = bf2f(r.y >> 16);
  o[4] = bf2f(r.z & 0xffffu); o[5] = bf2f(r.z >> 16);
  o[6] = bf2f(r.w & 0xffffu); o[7] = bf2f(r.w >> 16);
}

// async global->LDS, 16 B per lane; LDS dest = wave-uniform base + lane*16
__device__ __forceinline__ void gl_lds16(const unsigned short* g, unsigned short* l) {
  __builtin_amdgcn_global_load_lds(
      (const __attribute__((address_space(1))) void*)g,
      (__attribute__((address_space(3))) void*)l, 16, 0, 0);
}

// ---------------- prep: x fp32 -> bf16; transpose-convert weights ----------------
__global__ __launch_bounds__(256) void prep_kernel(
    const float* __restrict__ x, const float* __restrict__ wqkv, const float* __restrict__ wout,
    unsigned short* __restrict__ xb, unsigned short* __restrict__ wqkvT,
    unsigned short* __restrict__ woutT) {
  const int blk = blockIdx.x;
  if (blk < 16384) {
    const size_t i = ((size_t)blk * 256 + threadIdx.x) * 4;
    const float4 v = *(const float4*)(x + i);
    *(ushort4*)(xb + i) = make_ushort4(f2bf(v.x), f2bf(v.y), f2bf(v.z), f2bf(v.w));
  } else if (blk < 16384 + 768) {
    const int n = blk - 16384, k = threadIdx.x;            // wqkvT[n][k] = wqkv[k][n]
    wqkvT[n * 256 + k] = f2bf(wqkv[(size_t)k * 768 + n]);
  } else {
    const int c = blk - 16384 - 768, f = threadIdx.x;      // woutT[c][f] = wout[f][c]
    woutT[c * 256 + f] = f2bf(wout[(size_t)f * 256 + c]);
  }
}

// ------------- GEMM (m97 structure): D = A[M][K] * BT[N][K]^T, bf16 MFMA ---------
// 128x128 tile, BK=64, linear LDS [128][64], global_load_lds width-16 staging,
// 4 waves (2x2), 4x4 frags of 16x16x32. QSOFT: bn<2 tiles get per-head softmax
// epilogue written to QS (q-hat); bn>=2 write D at colbase (bn-2)*128.
template <typename OutT, bool QSOFT, bool SWZ>
__global__ __launch_bounds__(256) void gemm_bt(
    const unsigned short* __restrict__ A, const unsigned short* __restrict__ BT,
    OutT* __restrict__ D, unsigned short* __restrict__ QS,
    int nbn, int K, int N,
    size_t strideA, size_t strideB, size_t strideD) {
  __shared__ unsigned short As[128 * 64];
  __shared__ unsigned short Bs[128 * 64];
  int lin = blockIdx.x;
  if (SWZ) {  // XCD-aware chunked remap (gridDim.x % 8 == 0 -> bijective)
    const int cpx = gridDim.x >> 3;
    lin = (lin & 7) * cpx + (lin >> 3);
  }
  const int bn = lin % nbn, bm = lin / nbn, bz = blockIdx.z;
  const int tid = threadIdx.x, lane = tid & 63, wid = tid >> 6;
  const int wr = wid >> 1, wc = wid & 1;
  const int fr = lane & 15, hi = lane >> 4;
  f32x4 acc[4][4] = {};
  const unsigned short* Ab = A + (size_t)bz * strideA + (size_t)bm * 128 * K;
  const unsigned short* Bb = BT + (size_t)bz * strideB + (size_t)bn * 128 * K;

  // staging: wave w issue i covers LDS rows [w*32+i*8, +8); lane l -> row +(l>>3),
  // col shorts (l&7)*8  (matches LDS-linear lane*16B rule)
  const int srow = wid * 32 + (lane >> 3);
  const int scol = (lane & 7) * 8;
  const unsigned short* Ap = Ab + (size_t)srow * K + scol;
  const unsigned short* Bp = Bb + (size_t)srow * K + scol;
  unsigned short* Asw = As + (wid * 4) * 512 + 0;  // +i*512 shorts per issue
  unsigned short* Bsw = Bs + (wid * 4) * 512 + 0;

  for (int kt = 0; kt < K; kt += 64) {
#pragma unroll
    for (int i = 0; i < 4; ++i) {
      gl_lds16(Ap + (size_t)i * 8 * K + kt, Asw + i * 512);
      gl_lds16(Bp + (size_t)i * 8 * K + kt, Bsw + i * 512);
    }
    __syncthreads();  // drains vmcnt -> LDS tiles complete
#pragma unroll
    for (int kk = 0; kk < 2; ++kk) {
      short8 af[4], bfv[4];
#pragma unroll
      for (int i = 0; i < 4; ++i) {
        af[i]  = *(const short8*)&As[(wr * 64 + i * 16 + fr) * 64 + kk * 32 + hi * 8];
        bfv[i] = *(const short8*)&Bs[(wc * 64 + i * 16 + fr) * 64 + kk * 32 + hi * 8];
      }
#pragma unroll
      for (int mi = 0; mi < 4; ++mi)
#pragma unroll
        for (int nj = 0; nj < 4; ++nj)
          acc[mi][nj] = __builtin_amdgcn_mfma_f32_16x16x32_bf16(af[mi], bfv[nj], acc[mi][nj], 0, 0, 0);
    }
    __syncthreads();  // all reads done before next stage overwrites
  }

  // C/D layout (HW-verified): col = lane&15, row = (lane>>4)*4 + reg
  const size_t r0 = (size_t)bm * 128 + wr * 64;
  if (QSOFT && bn < 2) {
    // fused q-softmax over d=32 (cols [c0+p*32, +32) = nj pair {2p,2p+1});
    // reduce across the 16 fr-lanes (masks<16 keep hi-group) then scale, bf16 out.
    const int c0 = bn * 128 + wc * 64;
#pragma unroll
    for (int mi = 0; mi < 4; ++mi)
#pragma unroll
      for (int p = 0; p < 2; ++p)
#pragma unroll
        for (int r = 0; r < 4; ++r) {
          const float v0 = acc[mi][2 * p][r], v1 = acc[mi][2 * p + 1][r];
          float mx = fmaxf(v0, v1);
#pragma unroll
          for (int xm = 1; xm < 16; xm <<= 1) mx = fmaxf(mx, __shfl_xor(mx, xm, 64));
          const float e0 = __expf(v0 - mx), e1 = __expf(v1 - mx);
          float s = e0 + e1;
#pragma unroll
          for (int xm = 1; xm < 16; xm <<= 1) s += __shfl_xor(s, xm, 64);
          const float inv = SCALE_Q / s;
          const size_t row = r0 + mi * 16 + hi * 4 + r;
          QS[row * 256 + c0 + p * 32 + fr]      = f2bf(e0 * inv);
          QS[row * 256 + c0 + p * 32 + 16 + fr] = f2bf(e1 * inv);
        }
    return;
  }
  const int colbase = (QSOFT ? (bn - 2) : bn) * 128 + wc * 64;
  OutT* Dz = D + (size_t)bz * strideD;
#pragma unroll
  for (int mi = 0; mi < 4; ++mi)
#pragma unroll
    for (int nj = 0; nj < 4; ++nj) {
      const int col = colbase + nj * 16 + fr;
#pragma unroll
      for (int r = 0; r < 4; ++r) {
        const size_t row = r0 + mi * 16 + hi * 4 + r;
        const float v = acc[mi][nj][r];
        if constexpr (sizeof(OutT) == 2) Dz[row * N + col] = (OutT)f2bf(v);
        else                             Dz[row * N + col] = v;
      }
    }
}

// ---------------- ctx partials: per (b,h,chunk): sum_n exp(k[d,n])*v[e,n] ---------
// kv layout [65536][512]: k at cols 0..255, v at 256..511. No max-subtraction
// (k ~ N(0,1), fp32-safe); normalization in combine.
__global__ __launch_bounds__(256) void ctx_part_kernel(const unsigned short* __restrict__ kv,
                                                       float* __restrict__ part,
                                                       float* __restrict__ spart) {
  const int blk = blockIdx.x;
  const int bh = blk >> 4, chunk = blk & 15;
  const int b = bh >> 3, h = bh & 7;
  const int tid = threadIdx.x, d = tid & 31, g = tid >> 5;
  const unsigned short* kbase =
      kv + (size_t)b * 4096 * 512 + h * 32 + (size_t)chunk * 256 * 512;
  const unsigned short* vbase = kbase + 256;

  __shared__ float ek[64][36], vv[64][36];
  float a0 = 0.f, a1 = 0.f, a2 = 0.f, a3 = 0.f, ssum = 0.f;
  const int e0 = g * 4;
  const int sn = tid >> 2, sc = (tid & 3) * 8;
  const unsigned short* kp0 = kbase + (size_t)sn * 512 + sc;
  const unsigned short* vp0 = vbase + (size_t)sn * 512 + sc;
  uint4 kr = *(const uint4*)kp0;
  uint4 vr = *(const uint4*)vp0;
  for (int n0 = 0; n0 < 256; n0 += 64) {
    float kf[8], vf[8];
    bf8_to_f(kr, kf); bf8_to_f(vr, vf);
    uint4 krn = kr, vrn = vr;
    if (n0 + 64 < 256) {  // prefetch next sub-chunk under this one's compute
      krn = *(const uint4*)(kp0 + (size_t)(n0 + 64) * 512);
      vrn = *(const uint4*)(vp0 + (size_t)(n0 + 64) * 512);
    }
#pragma unroll
    for (int j = 0; j < 8; ++j) { ek[sn][sc + j] = __expf(kf[j]); vv[sn][sc + j] = vf[j]; }
    __syncthreads();
#pragma unroll 8
    for (int i = 0; i < 64; ++i) {
      const float kd = ek[i][d];
      const float4 v4 = *(const float4*)&vv[i][e0];
      ssum += kd;
      a0 += kd * v4.x; a1 += kd * v4.y; a2 += kd * v4.z; a3 += kd * v4.w;
    }
    __syncthreads();
    kr = krn; vr = vrn;
  }
  float* pp = part + ((size_t)chunk * 128 + bh) * 1024 + d * 32 + e0;
  pp[0] = a0; pp[1] = a1; pp[2] = a2; pp[3] = a3;
  if (g == 0) spart[((size_t)chunk * 128 + bh) * 32 + d] = ssum;
}

// ---------------- ctx combine: ctx[d][e] = sum_c part / sum_c spart ---------------
__global__ __launch_bounds__(256) void ctx_combine_kernel(const float* __restrict__ part,
                                                          const float* __restrict__ spart,
                                                          float* __restrict__ ctx) {
  const int bh = blockIdx.x, tid = threadIdx.x;
  __shared__ float sinv[32];
  if (tid < 32) {
    float s = 0.f;
#pragma unroll
    for (int c = 0; c < NCHUNK; ++c) s += spart[((size_t)c * 128 + bh) * 32 + tid];
    sinv[tid] = 1.0f / s;
  }
  __syncthreads();
  float4 acc = make_float4(0.f, 0.f, 0.f, 0.f);
#pragma unroll
  for (int c = 0; c < NCHUNK; ++c) {
    const float4 p = *(const float4*)(part + ((size_t)c * 128 + bh) * 1024 + tid * 4);
    acc.x += p.x; acc.y += p.y; acc.z += p.z; acc.w += p.w;
  }
  const float si = sinv[tid >> 3];  // d = (tid*4)>>5
  float4* cp = (float4*)(ctx + (size_t)bh * 1024 + tid * 4);
  *cp = make_float4(acc.x * si, acc.y * si, acc.z * si, acc.w * si);
}

// ---------------- w2: W2T[b][c][(h,d)] = sum_e ctx[b,h,d,e] * woutT[c][(h,e)] -----
__global__ __launch_bounds__(256) void w2_kernel(const float* __restrict__ ctx,
                                                 const unsigned short* __restrict__ woutT,
                                                 unsigned short* __restrict__ W2T) {
  const int b = blockIdx.x >> 4, cg = blockIdx.x & 15;
  const int tid = threadIdx.x;
  __shared__ float cs[8 * 32 * 32];  // ctx[b]: 8 heads x 32d x 32e = 32 KB
  {
    const float4* src = (const float4*)(ctx + (size_t)b * 8192);
    float4* dst = (float4*)cs;
#pragma unroll
    for (int i = 0; i < 8; ++i) dst[tid + i * 256] = src[tid + i * 256];
  }
  __syncthreads();
  const int c = cg * 16 + (tid >> 4), chunk = tid & 15;
  const int h = chunk >> 1, d0 = (chunk & 1) * 16;
  float wf[32];
  {
    const uint4* wp = (const uint4*)(woutT + (size_t)c * 256 + h * 32);
    bf8_to_f(wp[0], wf + 0); bf8_to_f(wp[1], wf + 8);
    bf8_to_f(wp[2], wf + 16); bf8_to_f(wp[3], wf + 24);
  }
  unsigned short o[16];
#pragma unroll
  for (int dd = 0; dd < 16; ++dd) {
    const float* cp = cs + h * 1024 + (d0 + dd) * 32;
    float acc = 0.f;
#pragma unroll
    for (int e = 0; e < 32; ++e) acc += cp[e] * wf[e];
    o[dd] = f2bf(acc);
  }
  uint4* op = (uint4*)(W2T + ((size_t)b * 256 + c) * 256 + chunk * 16);
  op[0] = make_uint4((unsigned)o[0] | ((unsigned)o[1] << 16), (unsigned)o[2] | ((unsigned)o[3] << 16),
                     (unsigned)o[4] | ((unsigned)o[5] << 16), (unsigned)o[6] | ((unsigned)o[7] << 16));
  op[1] = make_uint4((unsigned)o[8] | ((unsigned)o[9] << 16), (unsigned)o[10] | ((unsigned)o[11] << 16),
                     (unsigned)o[12] | ((unsigned)o[13] << 16), (unsigned)o[14] | ((unsigned)o[15] << 16));
}

extern "C" void kernel_launch(void* const* d_in, const int* in_sizes, int n_in,
                              void* d_out, int out_size, void* d_ws, size_t ws_size,
                              hipStream_t stream) {
  const float* x     = (const float*)d_in[0];  // [16,64,64,256]
  const float* wqkv  = (const float*)d_in[1];  // [256,768]
  const float* wout  = (const float*)d_in[2];  // [256,256]
  float* out = (float*)d_out;                  // [65536,256] fp32

  char* ws = (char*)d_ws;
  unsigned short* xb    = (unsigned short*)(ws);                 // 32 MB (dead after gemm1)
  unsigned short* wqkvT = (unsigned short*)(ws + 33554432);      // 384 KB
  unsigned short* woutT = (unsigned short*)(ws + 33947648);      // 128 KB
  unsigned short* kv    = (unsigned short*)(ws + 34078720);      // 64 MB [65536][512]
  float*          ctx   = (float*)        (ws + 101187584);      // 512 KB [128][32][32]
  unsigned short* qs    = (unsigned short*)(ws + 101711872);     // 32 MB [65536][256]
  // reuse xb region (dead after gemm1):
  float*          part  = (float*)(ws);                          // 8 MB [16][128][1024]
  float*          spart = (float*)(ws + 8388608);                // 256 KB [16][128][32]
  unsigned short* W2T   = (unsigned short*)(ws + 12582912);      // 2 MB [16][256][256]

  prep_kernel<<<16384 + 768 + 256, 256, 0, stream>>>(x, wqkv, wout, xb, wqkvT, woutT);
  // gemm1: M=65536 N(logical)=768 K=256; q tiles (bn<2) -> fused softmax into qs,
  // k/v tiles -> kv[65536][512]. 1D grid 3072 = 6 bn x 512 bm, XCD-swizzled.
  gemm_bt<unsigned short, true, true><<<3072, 256, 0, stream>>>(
      xb, wqkvT, kv, qs, 6, 256, 512, 0, 0, 0);
  ctx_part_kernel<<<2048, 256, 0, stream>>>(kv, part, spart);
  ctx_combine_kernel<<<128, 256, 0, stream>>>(part, spart, ctx);
  w2_kernel<<<256, 256, 0, stream>>>(ctx, woutT, W2T);
  // gemm2: batched z=16, M=4096 N=256 K=256; grid.x = 2 bn x 32 bm.
  gemm_bt<float, false, false><<<dim3(64, 1, 16), 256, 0, stream>>>(
      qs, W2T, out, nullptr, 2, 256, 256, (size_t)4096 * 256, (size_t)256 * 256, (size_t)4096 * 256);
}